// Round 1
// baseline (2601.678 us; speedup 1.0000x reference)
//
#include <hip/hip_runtime.h>
#include <math.h>

#define DE 768
#define DP 320
#define HID 768
#define LL 512
#define BB 64
#define M_TOT (BB * LL)   // 32768 rows

// ---- monotone float <-> uint key (for max via unsigned atomicMax) ----
__device__ __forceinline__ unsigned fkey(float v) {
    unsigned u = __float_as_uint(v);
    return (u & 0x80000000u) ? ~u : (u | 0x80000000u);
}
__device__ __forceinline__ float funkey(unsigned k) {
    unsigned u = (k & 0x80000000u) ? (k & 0x7FFFFFFFu) : ~k;
    return __uint_as_float(u);
}

// ---- transpose Wc[h][d][k] -> WcT[k][h][d] for coalesced B-tile loads ----
__global__ void prep_wc(const float* __restrict__ Wc, float* __restrict__ WcT) {
    int idx = blockIdx.x * blockDim.x + threadIdx.x;
    if (idx >= 3 * HID * DE) return;
    int k = idx / (HID * DE);
    int rem = idx - k * (HID * DE);
    int h = rem / DE;
    int d = rem - h * DE;
    WcT[idx] = Wc[(h * DE + d) * 3 + k];
}

// ---- K1: X = sigmoid(Xe*W1^T+b1)*Xe + (1-sig)*tanh(Xp*W2^T+b2) ----
// 64x64 tile, 256 threads, 4x4 per thread, transposed LDS tiles (k-major)
__global__ __launch_bounds__(256) void gate_kernel(
    const float* __restrict__ Xe, const float* __restrict__ Xp,
    const float* __restrict__ W1, const float* __restrict__ b1,
    const float* __restrict__ W2, const float* __restrict__ b2,
    float* __restrict__ Xout)
{
    __shared__ __align__(16) float As[16][68];
    __shared__ __align__(16) float Bs[16][68];
    const int tid = threadIdx.x;
    const int tx = tid & 15, ty = tid >> 4;
    const int m0 = blockIdx.x * 64;
    const int n0 = blockIdx.y * 64;
    const int lc = tid & 15, lr = tid >> 4;

    float acc1[4][4] = {};
    for (int k0 = 0; k0 < DE; k0 += 16) {
        __syncthreads();
        #pragma unroll
        for (int r = 0; r < 4; ++r) {
            int arow = lr + 16 * r;
            As[lc][arow] = Xe[(size_t)(m0 + arow) * DE + k0 + lc];
            Bs[lc][arow] = W1[(size_t)(n0 + arow) * DE + k0 + lc];
        }
        __syncthreads();
        #pragma unroll
        for (int kk = 0; kk < 16; ++kk) {
            float4 av = *(const float4*)&As[kk][ty * 4];
            float4 bv = *(const float4*)&Bs[kk][tx * 4];
            const float a[4] = {av.x, av.y, av.z, av.w};
            const float b[4] = {bv.x, bv.y, bv.z, bv.w};
            #pragma unroll
            for (int i = 0; i < 4; ++i)
                #pragma unroll
                for (int j = 0; j < 4; ++j)
                    acc1[i][j] = fmaf(a[i], b[j], acc1[i][j]);
        }
    }

    float acc2[4][4] = {};
    for (int k0 = 0; k0 < DP; k0 += 16) {
        __syncthreads();
        #pragma unroll
        for (int r = 0; r < 4; ++r) {
            int arow = lr + 16 * r;
            As[lc][arow] = Xp[(size_t)(m0 + arow) * DP + k0 + lc];
            Bs[lc][arow] = W2[(size_t)(n0 + arow) * DP + k0 + lc];
        }
        __syncthreads();
        #pragma unroll
        for (int kk = 0; kk < 16; ++kk) {
            float4 av = *(const float4*)&As[kk][ty * 4];
            float4 bv = *(const float4*)&Bs[kk][tx * 4];
            const float a[4] = {av.x, av.y, av.z, av.w};
            const float b[4] = {bv.x, bv.y, bv.z, bv.w};
            #pragma unroll
            for (int i = 0; i < 4; ++i)
                #pragma unroll
                for (int j = 0; j < 4; ++j)
                    acc2[i][j] = fmaf(a[i], b[j], acc2[i][j]);
        }
    }

    #pragma unroll
    for (int i = 0; i < 4; ++i) {
        int row = m0 + ty * 4 + i;
        #pragma unroll
        for (int j = 0; j < 4; ++j) {
            int o = n0 + tx * 4 + j;
            float g = 1.f / (1.f + __expf(-(acc1[i][j] + b1[o])));
            float t = tanhf(acc2[i][j] + b2[o]);
            float xe = Xe[(size_t)row * DE + o];
            Xout[(size_t)row * DE + o] = g * xe + (1.f - g) * t;
        }
    }
}

// ---- K2: conv1d(width 3, pad 1) as 3 shifted GEMMs + fused masked max-pool ----
__global__ __launch_bounds__(256) void conv_pool_kernel(
    const float* __restrict__ X, const float* __restrict__ WcT,
    const float* __restrict__ bc, const int* __restrict__ mask,
    unsigned* __restrict__ pool)
{
    __shared__ __align__(16) float As[16][68];
    __shared__ __align__(16) float Bs[16][68];
    __shared__ unsigned lpool[64][3];
    __shared__ int anyNot[3];

    const int tid = threadIdx.x;
    const int tx = tid & 15, ty = tid >> 4;
    const int m0 = blockIdx.x * 64;
    const int n0 = blockIdx.y * 64;
    const int b  = m0 >> 9;       // 512 rows per batch
    const int l0 = m0 & 511;
    const int lc = tid & 15, lr = tid >> 4;

    if (tid < 3) anyNot[tid] = 0;
    if (tid < 192) ((unsigned*)lpool)[tid] = 0u;   // identity for unsigned max
    __syncthreads();
    if (tid < 64) {
        int mv = mask[b * LL + l0 + tid];
        #pragma unroll
        for (int k = 0; k < 3; ++k)
            if (mv != k + 1) atomicOr(&anyNot[k], 1);
    }

    float acc[4][4] = {};
    for (int s = 0; s < 3; ++s) {
        const float* Bk = WcT + (size_t)s * HID * DE;
        for (int k0 = 0; k0 < DE; k0 += 16) {
            __syncthreads();
            #pragma unroll
            for (int r = 0; r < 4; ++r) {
                int arow = lr + 16 * r;
                int lp = l0 + arow + s - 1;
                As[lc][arow] = (lp >= 0 && lp < LL)
                    ? X[((size_t)b * LL + lp) * DE + k0 + lc] : 0.f;
                Bs[lc][arow] = Bk[(size_t)(n0 + arow) * DE + k0 + lc];
            }
            __syncthreads();
            #pragma unroll
            for (int kk = 0; kk < 16; ++kk) {
                float4 av = *(const float4*)&As[kk][ty * 4];
                float4 bv = *(const float4*)&Bs[kk][tx * 4];
                const float a[4] = {av.x, av.y, av.z, av.w};
                const float bb[4] = {bv.x, bv.y, bv.z, bv.w};
                #pragma unroll
                for (int i = 0; i < 4; ++i)
                    #pragma unroll
                    for (int j = 0; j < 4; ++j)
                        acc[i][j] = fmaf(a[i], bb[j], acc[i][j]);
            }
        }
    }

    __syncthreads();
    #pragma unroll
    for (int i = 0; i < 4; ++i) {
        int l = l0 + ty * 4 + i;
        int mv = mask[b * LL + l];
        int kseg = mv - 1;
        if (kseg >= 0) {
            #pragma unroll
            for (int j = 0; j < 4; ++j) {
                float y = acc[i][j] + bc[n0 + tx * 4 + j];
                atomicMax(&lpool[tx * 4 + j][kseg], fkey(y));
            }
        }
    }
    __syncthreads();
    if (tid < 192) {
        int hl = tid / 3, k = tid - hl * 3;
        unsigned key = lpool[hl][k];
        if (anyNot[k]) {
            unsigned z = fkey(0.0f);
            if (z > key) key = z;
        }
        atomicMax(&pool[((size_t)b * HID + n0 + hl) * 3 + k], key);
    }
}

// ---- K3: out = tanh(untransform(pool)) ----
__global__ void finish_k(const unsigned* __restrict__ pool, float* __restrict__ out) {
    int idx = blockIdx.x * blockDim.x + threadIdx.x;
    if (idx < BB * HID * 3) out[idx] = tanhf(funkey(pool[idx]));
}

extern "C" void kernel_launch(void* const* d_in, const int* in_sizes, int n_in,
                              void* d_out, int out_size, void* d_ws, size_t ws_size,
                              hipStream_t stream) {
    const float* Xp = (const float*)d_in[0];
    const float* Xe = (const float*)d_in[1];
    const int*   Xm = (const int*)d_in[2];
    const float* W1 = (const float*)d_in[3];
    const float* b1 = (const float*)d_in[4];
    const float* W2 = (const float*)d_in[5];
    const float* b2 = (const float*)d_in[6];
    const float* Wc = (const float*)d_in[7];
    const float* bc = (const float*)d_in[8];
    float* out = (float*)d_out;

    float* Xbuf = (float*)d_ws;                          // 32768*768 f32 = 96 MB
    float* WcT  = Xbuf + (size_t)M_TOT * DE;             // 3*768*768 f32 = 7 MB
    unsigned* pool = (unsigned*)(WcT + (size_t)3 * HID * DE);  // 64*768*3 u32

    hipMemsetAsync(pool, 0, (size_t)BB * HID * 3 * sizeof(unsigned), stream);
    prep_wc<<<(3 * HID * DE + 255) / 256, 256, 0, stream>>>(Wc, WcT);
    gate_kernel<<<dim3(M_TOT / 64, DE / 64), 256, 0, stream>>>(
        Xe, Xp, W1, b1, W2, b2, Xbuf);
    conv_pool_kernel<<<dim3(M_TOT / 64, HID / 64), 256, 0, stream>>>(
        Xbuf, WcT, bc, Xm, pool);
    finish_k<<<(BB * HID * 3 + 255) / 256, 256, 0, stream>>>(pool, out);
}

// Round 2
// 587.671 us; speedup vs baseline: 4.4271x; 4.4271x over previous
//
#include <hip/hip_runtime.h>
#include <math.h>

#define DE 768
#define DP 320
#define HID 768
#define LL 512
#define BB 64
#define M_TOT (BB * LL)   // 32768 rows

typedef _Float16 half8 __attribute__((ext_vector_type(8)));
typedef float floatx4 __attribute__((ext_vector_type(4)));

// ---- monotone float <-> uint key (for max via unsigned atomicMax) ----
__device__ __forceinline__ unsigned fkey(float v) {
    unsigned u = __float_as_uint(v);
    return (u & 0x80000000u) ? ~u : (u | 0x80000000u);
}
__device__ __forceinline__ float funkey(unsigned k) {
    unsigned u = (k & 0x80000000u) ? (k & 0x7FFFFFFFu) : ~k;
    return __uint_as_float(u);
}

// ---- Wc[h][d][s] -> WcT[s][h][d] fp16 for coalesced B-tile loads ----
__global__ void prep_wc(const float* __restrict__ Wc, _Float16* __restrict__ WcT) {
    int idx = blockIdx.x * 256 + threadIdx.x;
    if (idx >= 3 * HID * DE) return;
    int s = idx / (HID * DE);
    int rem = idx - s * (HID * DE);
    int h = rem / DE;
    int d = rem - h * DE;
    WcT[idx] = (_Float16)Wc[(h * DE + d) * 3 + s];
}

// ---- K1: X = sigmoid(Xe*W1^T+b1)*Xe + (1-sig)*tanh(Xp*W2^T+b2), fp16 MFMA ----
__global__ __launch_bounds__(256) void gate_kernel(
    const float* __restrict__ Xe, const float* __restrict__ Xp,
    const float* __restrict__ W1, const float* __restrict__ b1,
    const float* __restrict__ W2, const float* __restrict__ b2,
    _Float16* __restrict__ Xout)
{
    __shared__ __align__(16) _Float16 As[128][32];
    __shared__ __align__(16) _Float16 Bs[128][32];
    const int tid = threadIdx.x;
    const int lane = tid & 63, wid = tid >> 6;
    const int quad = lane >> 4, l15 = lane & 15;
    const int wm = (wid & 1) * 64, wn = (wid >> 1) * 64;
    const int m0 = blockIdx.y * 128, n0 = blockIdx.x * 128;
    const int srow = (tid * 8) >> 5;   // 0..63
    const int scol = (tid * 8) & 31;

    floatx4 acc1[4][4] = {};
    floatx4 acc2[4][4] = {};

    // GEMM1: Xe (K=768) x W1^T
    for (int k0 = 0; k0 < DE; k0 += 32) {
        __syncthreads();
        #pragma unroll
        for (int hh = 0; hh < 2; ++hh) {
            int r = srow + hh * 64;
            const float* ga = &Xe[(size_t)(m0 + r) * DE + k0 + scol];
            float4 a0 = *(const float4*)ga, a1 = *(const float4*)(ga + 4);
            half8 av = {(_Float16)a0.x, (_Float16)a0.y, (_Float16)a0.z, (_Float16)a0.w,
                        (_Float16)a1.x, (_Float16)a1.y, (_Float16)a1.z, (_Float16)a1.w};
            *(half8*)&As[r][scol] = av;
            const float* gb = &W1[(size_t)(n0 + r) * DE + k0 + scol];
            float4 b0 = *(const float4*)gb, b1q = *(const float4*)(gb + 4);
            half8 bv = {(_Float16)b0.x, (_Float16)b0.y, (_Float16)b0.z, (_Float16)b0.w,
                        (_Float16)b1q.x, (_Float16)b1q.y, (_Float16)b1q.z, (_Float16)b1q.w};
            *(half8*)&Bs[r][scol] = bv;
        }
        __syncthreads();
        half8 af[4], bf[4];
        #pragma unroll
        for (int i = 0; i < 4; ++i) af[i] = *(half8*)&As[wm + i * 16 + l15][quad * 8];
        #pragma unroll
        for (int j = 0; j < 4; ++j) bf[j] = *(half8*)&Bs[wn + j * 16 + l15][quad * 8];
        #pragma unroll
        for (int i = 0; i < 4; ++i)
            #pragma unroll
            for (int j = 0; j < 4; ++j)
                acc1[i][j] = __builtin_amdgcn_mfma_f32_16x16x32_f16(af[i], bf[j], acc1[i][j], 0, 0, 0);
    }

    // GEMM2: Xp (K=320) x W2^T
    for (int k0 = 0; k0 < DP; k0 += 32) {
        __syncthreads();
        #pragma unroll
        for (int hh = 0; hh < 2; ++hh) {
            int r = srow + hh * 64;
            const float* ga = &Xp[(size_t)(m0 + r) * DP + k0 + scol];
            float4 a0 = *(const float4*)ga, a1 = *(const float4*)(ga + 4);
            half8 av = {(_Float16)a0.x, (_Float16)a0.y, (_Float16)a0.z, (_Float16)a0.w,
                        (_Float16)a1.x, (_Float16)a1.y, (_Float16)a1.z, (_Float16)a1.w};
            *(half8*)&As[r][scol] = av;
            const float* gb = &W2[(size_t)(n0 + r) * DP + k0 + scol];
            float4 b0 = *(const float4*)gb, b1q = *(const float4*)(gb + 4);
            half8 bv = {(_Float16)b0.x, (_Float16)b0.y, (_Float16)b0.z, (_Float16)b0.w,
                        (_Float16)b1q.x, (_Float16)b1q.y, (_Float16)b1q.z, (_Float16)b1q.w};
            *(half8*)&Bs[r][scol] = bv;
        }
        __syncthreads();
        half8 af[4], bf[4];
        #pragma unroll
        for (int i = 0; i < 4; ++i) af[i] = *(half8*)&As[wm + i * 16 + l15][quad * 8];
        #pragma unroll
        for (int j = 0; j < 4; ++j) bf[j] = *(half8*)&Bs[wn + j * 16 + l15][quad * 8];
        #pragma unroll
        for (int i = 0; i < 4; ++i)
            #pragma unroll
            for (int j = 0; j < 4; ++j)
                acc2[i][j] = __builtin_amdgcn_mfma_f32_16x16x32_f16(af[i], bf[j], acc2[i][j], 0, 0, 0);
    }

    // epilogue: C[m][n] with m = wm+i*16+quad*4+r, n = wn+j*16+l15
    #pragma unroll
    for (int j = 0; j < 4; ++j) {
        int o = n0 + wn + j * 16 + l15;
        float b1v = b1[o], b2v = b2[o];
        #pragma unroll
        for (int i = 0; i < 4; ++i) {
            #pragma unroll
            for (int r = 0; r < 4; ++r) {
                int row = m0 + wm + i * 16 + quad * 4 + r;
                float g = 1.f / (1.f + expf(-(acc1[i][j][r] + b1v)));
                float t = tanhf(acc2[i][j][r] + b2v);
                float xe = Xe[(size_t)row * DE + o];
                Xout[(size_t)row * DE + o] = (_Float16)(g * xe + (1.f - g) * t);
            }
        }
    }
}

// ---- K2: conv1d(width 3, pad 1) as 3 shifted MFMA GEMMs + fused masked max-pool ----
__global__ __launch_bounds__(256) void conv_pool_kernel(
    const _Float16* __restrict__ X, const _Float16* __restrict__ WcT,
    const float* __restrict__ bc, const int* __restrict__ mask,
    unsigned* __restrict__ pool)
{
    __shared__ __align__(16) _Float16 As[128][32];
    __shared__ __align__(16) _Float16 Bs[128][32];
    __shared__ unsigned lpool[128 * 3];
    __shared__ int smask[128];
    __shared__ int anyNot[3];

    const int tid = threadIdx.x;
    const int lane = tid & 63, wid = tid >> 6;
    const int quad = lane >> 4, l15 = lane & 15;
    const int wm = (wid & 1) * 64, wn = (wid >> 1) * 64;
    const int m0 = blockIdx.y * 128, n0 = blockIdx.x * 128;
    const int b = m0 >> 9, l0 = m0 & 511;
    const int srow = (tid * 8) >> 5;
    const int scol = (tid * 8) & 31;

    if (tid < 3) anyNot[tid] = 0;
    for (int i = tid; i < 384; i += 256) lpool[i] = 0u;   // identity for key-max
    if (tid < 128) smask[tid] = mask[b * LL + l0 + tid];
    __syncthreads();
    if (tid < 128) {
        int mv = smask[tid];
        if (mv != 1) atomicOr(&anyNot[0], 1);
        if (mv != 2) atomicOr(&anyNot[1], 1);
        if (mv != 3) atomicOr(&anyNot[2], 1);
    }

    floatx4 acc[4][4] = {};
    for (int s = 0; s < 3; ++s) {
        const _Float16* Bk = WcT + (size_t)s * HID * DE;
        for (int k0 = 0; k0 < DE; k0 += 32) {
            __syncthreads();
            #pragma unroll
            for (int hh = 0; hh < 2; ++hh) {
                int r = srow + hh * 64;
                int l = l0 + r + s - 1;
                uint4 av = make_uint4(0u, 0u, 0u, 0u);
                if ((unsigned)l < LL)
                    av = *(const uint4*)&X[((size_t)b * LL + l) * DE + k0 + scol];
                *(uint4*)&As[r][scol] = av;
                *(uint4*)&Bs[r][scol] = *(const uint4*)&Bk[(size_t)(n0 + r) * DE + k0 + scol];
            }
            __syncthreads();
            half8 af[4], bf[4];
            #pragma unroll
            for (int i = 0; i < 4; ++i) af[i] = *(half8*)&As[wm + i * 16 + l15][quad * 8];
            #pragma unroll
            for (int j = 0; j < 4; ++j) bf[j] = *(half8*)&Bs[wn + j * 16 + l15][quad * 8];
            #pragma unroll
            for (int i = 0; i < 4; ++i)
                #pragma unroll
                for (int j = 0; j < 4; ++j)
                    acc[i][j] = __builtin_amdgcn_mfma_f32_16x16x32_f16(af[i], bf[j], acc[i][j], 0, 0, 0);
        }
    }

    // epilogue: per-thread pre-reduction over the 16 rows this lane owns
    float tmax[4][3];
    #pragma unroll
    for (int j = 0; j < 4; ++j)
        #pragma unroll
        for (int sg = 0; sg < 3; ++sg) tmax[j][sg] = -1e38f;

    #pragma unroll
    for (int i = 0; i < 4; ++i) {
        #pragma unroll
        for (int r = 0; r < 4; ++r) {
            int ll = wm + i * 16 + quad * 4 + r;
            int seg = smask[ll] - 1;
            if (seg >= 0) {
                #pragma unroll
                for (int j = 0; j < 4; ++j)
                    tmax[j][seg] = fmaxf(tmax[j][seg], acc[i][j][r]);
            }
        }
    }
    #pragma unroll
    for (int j = 0; j < 4; ++j) {
        int h = wn + j * 16 + l15;
        float bias = bc[n0 + h];
        #pragma unroll
        for (int sg = 0; sg < 3; ++sg)
            if (tmax[j][sg] > -1e37f)
                atomicMax(&lpool[h * 3 + sg], fkey(tmax[j][sg] + bias));
    }
    __syncthreads();
    for (int i = tid; i < 384; i += 256) {
        int hl = i / 3, k = i - hl * 3;
        unsigned key = lpool[i];
        if (anyNot[k]) {
            unsigned z = fkey(0.0f);
            if (z > key) key = z;
        }
        atomicMax(&pool[((size_t)b * HID + n0 + hl) * 3 + k], key);
    }
}

// ---- K3: out = tanh(untransform(pool)) ----
__global__ void finish_k(const unsigned* __restrict__ pool, float* __restrict__ out) {
    int idx = blockIdx.x * blockDim.x + threadIdx.x;
    if (idx < BB * HID * 3) out[idx] = tanhf(funkey(pool[idx]));
}

extern "C" void kernel_launch(void* const* d_in, const int* in_sizes, int n_in,
                              void* d_out, int out_size, void* d_ws, size_t ws_size,
                              hipStream_t stream) {
    const float* Xp = (const float*)d_in[0];
    const float* Xe = (const float*)d_in[1];
    const int*   Xm = (const int*)d_in[2];
    const float* W1 = (const float*)d_in[3];
    const float* b1 = (const float*)d_in[4];
    const float* W2 = (const float*)d_in[5];
    const float* b2 = (const float*)d_in[6];
    const float* Wc = (const float*)d_in[7];
    const float* bc = (const float*)d_in[8];
    float* out = (float*)d_out;

    _Float16* X_h  = (_Float16*)d_ws;                       // 32768*768 fp16 = 50.3 MB
    _Float16* Wc_h = X_h + (size_t)M_TOT * DE;              // 3*768*768 fp16 = 3.5 MB
    unsigned* pool = (unsigned*)(Wc_h + (size_t)3 * HID * DE);  // 64*768*3 u32

    hipMemsetAsync(pool, 0, (size_t)BB * HID * 3 * sizeof(unsigned), stream);
    prep_wc<<<(3 * HID * DE + 255) / 256, 256, 0, stream>>>(Wc, Wc_h);
    gate_kernel<<<dim3(DE / 128, M_TOT / 128), 256, 0, stream>>>(
        Xe, Xp, W1, b1, W2, b2, X_h);
    conv_pool_kernel<<<dim3(HID / 128, M_TOT / 128), 256, 0, stream>>>(
        X_h, Wc_h, bc, Xm, pool);
    finish_k<<<(BB * HID * 3 + 255) / 256, 256, 0, stream>>>(pool, out);
}